// Round 9
// baseline (1800.810 us; speedup 1.0000x reference)
//
#include <hip/hip_runtime.h>
#include <stdint.h>

#define T_TOK 1024
#define HD 2880
#define ID 2880
#define NE 16
#define NTOP 4
#define BK 64
#define NKT (HD / BK)          // 45

#define BM 128
#define BN 64
#define NIB (ID / BN)          // 45
#define NMB (T_TOK / BM)       // 8
#define NB (NE * NIB * NMB)    // 5760

typedef short bf16x8 __attribute__((ext_vector_type(8)));
typedef float f32x4 __attribute__((ext_vector_type(4)));

__device__ __forceinline__ uint4 pack8f(const float* v) {
    union { __bf16 b[8]; uint4 q; } p;
#pragma unroll
    for (int j = 0; j < 8; j++) p.b[j] = (__bf16)v[j];
    return p.q;
}
__device__ __forceinline__ unsigned short bf16bits(float f) {
    union { __bf16 b[2]; unsigned short u[2]; } p;
    p.b[0] = (__bf16)f;
    return p.u[0];
}

// ---------------- init ----------------
__global__ __launch_bounds__(256) void k_init(float* __restrict__ out, int* __restrict__ cnt) {
    int i = blockIdx.x * 256 + threadIdx.x;
    ((float4*)out)[i] = make_float4(0.f, 0.f, 0.f, 0.f);
    if (blockIdx.x == 0 && threadIdx.x < NE) cnt[threadIdx.x] = 0;
}

// ---------------- x -> bf16 ----------------
__global__ __launch_bounds__(256) void k_xbf(const float* __restrict__ x, unsigned short* __restrict__ xbf) {
    const size_t i = (size_t)blockIdx.x * 256 + threadIdx.x;
    float v[8];
    float4 a = ((const float4*)x)[i * 2];
    float4 b = ((const float4*)x)[i * 2 + 1];
    v[0] = a.x; v[1] = a.y; v[2] = a.z; v[3] = a.w;
    v[4] = b.x; v[5] = b.y; v[6] = b.z; v[7] = b.w;
    ((uint4*)xbf)[i] = pack8f(v);
}

// ---------------- router ----------------
__global__ __launch_bounds__(256) void k_router(
    const float* __restrict__ x, const float* __restrict__ rw, const float* __restrict__ rb,
    float* __restrict__ topw, int* __restrict__ cnt, int* __restrict__ list)
{
    const int t = blockIdx.x;
    const int tid = threadIdx.x;
    float acc[NE];
#pragma unroll
    for (int e = 0; e < NE; e++) acc[e] = 0.f;
    for (int c = tid; c < HD; c += 256) {
        float xv = x[(size_t)t * HD + c];
#pragma unroll
        for (int e = 0; e < NE; e++) acc[e] += xv * rw[(size_t)e * HD + c];
    }
    __shared__ float red[4][NE];
    const int lane = tid & 63, wv = tid >> 6;
#pragma unroll
    for (int e = 0; e < NE; e++) {
        float v = acc[e];
#pragma unroll
        for (int off = 32; off > 0; off >>= 1) v += __shfl_down(v, off, 64);
        if (lane == 0) red[wv][e] = v;
    }
    __syncthreads();
    if (tid == 0) {
        float p[NE];
        float mx = -1e30f;
        for (int e = 0; e < NE; e++) {
            float v = red[0][e] + red[1][e] + red[2][e] + red[3][e] + rb[e];
            p[e] = v; mx = fmaxf(mx, v);
        }
        for (int e = 0; e < NE; e++) p[e] = expf(p[e] - mx);
        int sel[NTOP]; float pw[NTOP]; float ssum = 0.f;
        for (int k = 0; k < NTOP; k++) {
            float best = -1.f; int bi = 0;
            for (int e = 0; e < NE; e++)
                if (p[e] > best) { best = p[e]; bi = e; }
            sel[k] = bi; pw[k] = best; ssum += best; p[bi] = -2.f;
        }
        for (int k = 0; k < NTOP; k++) {
            topw[t * NTOP + k] = pw[k] / ssum;
            int e = sel[k];
            int pos = atomicAdd(&cnt[e], 1);
            list[e * T_TOK + pos] = t * NTOP + k;
        }
    }
}

// ---------------- prefix scan ----------------
__global__ void k_scan(const int* __restrict__ cnt, int* __restrict__ offs) {
    if (threadIdx.x == 0 && blockIdx.x == 0) {
        int s = 0;
        for (int e = 0; e < NE; e++) { offs[e] = s; s += cnt[e]; }
        offs[NE] = s;
    }
}

// ---------------- GEMM1: barrier-free, wave-private B staging, in-wave swiglu ----------------
__global__ __launch_bounds__(256, 3) void k_gemm1(
    const unsigned short* __restrict__ xbf,
    const float* __restrict__ wg, const float* __restrict__ bg,
    const float* __restrict__ wu, const float* __restrict__ bu,
    const int* __restrict__ cnt, const int* __restrict__ offs,
    const int* __restrict__ list,
    unsigned short* __restrict__ act)
{
    const int lin = blockIdx.x;
    const int logical = (lin & 7) * (NB / 8) + (lin >> 3);
    const int mblk = logical & 7;
    const int iblk = (logical >> 3) % NIB;
    const int e = logical / (NIB * NMB);

    const int count = cnt[e];
    const int m0 = mblk * BM;
    if (m0 >= count) return;
    const int mcount = min(BM, count - m0);
    const int i0 = iblk * BN;
    const int tid = threadIdx.x;

    const int lane = tid & 63, wid = tid >> 6;
    const int mh = wid >> 1, nh = wid & 1;       // wave tile: 64m x 32i, G+U
    const int lr = lane & 15, lk = lane >> 4;

    // A row pointers (per-lane token gather; no LDS, no barrier)
    const unsigned short* arow[4];
#pragma unroll
    for (int mb = 0; mb < 4; mb++) {
        const int r = m0 + min(mh * 64 + mb * 16 + lr, mcount - 1);
        arow[mb] = xbf + (size_t)(list[e * T_TOK + r] >> 2) * HD;
    }

    // B staging: lane -> col c (32 cols), half -> k-rows [half*32, half*32+32)
    const int c = lane & 31, half = lane >> 5;
    const size_t wofs = ((size_t)e * HD + half * 32) * ID + (i0 + nh * 32 + c);
    const float* gsrc = wg + wofs;
    const float* usrc = wu + wofs;

    __shared__ __align__(16) char sB[4][8192];   // per-wave: rows 0..31 = G cols, 32..63 = U cols
    char* const wbuf = sB[wid];
    const int rowG = c, rowU = 32 + c;

    f32x4 accG[4][2], accU[4][2];
#pragma unroll
    for (int mb = 0; mb < 4; mb++)
#pragma unroll
        for (int cb = 0; cb < 2; cb++) {
            accG[mb][cb] = (f32x4){0.f, 0.f, 0.f, 0.f};
            accU[mb][cb] = (f32x4){0.f, 0.f, 0.f, 0.f};
        }

    {   // prologue: stage tile 0 (wave-local; lgkmcnt orders write->read)
        float gv[32], uv[32];
#pragma unroll
        for (int j = 0; j < 32; j++) gv[j] = gsrc[(size_t)j * ID];
#pragma unroll
        for (int j = 0; j < 32; j++) uv[j] = usrc[(size_t)j * ID];
#pragma unroll
        for (int jj = 0; jj < 4; jj++) {
            const int ch = half * 4 + jj;
            *(uint4*)(wbuf + rowG * 128 + ((ch ^ (rowG & 7)) * 16)) = pack8f(gv + jj * 8);
            *(uint4*)(wbuf + rowU * 128 + ((ch ^ (rowU & 7)) * 16)) = pack8f(uv + jj * 8);
        }
    }

    for (int kt = 0; kt < NKT; kt++) {
        const bool more = (kt + 1 < NKT);
        // A fragments for this kt (gathered 16B loads; L2-resident xbf)
        bf16x8 af[4][2];
#pragma unroll
        for (int mb = 0; mb < 4; mb++)
#pragma unroll
            for (int ks = 0; ks < 2; ks++)
                af[mb][ks] = *(const bf16x8*)(arow[mb] + kt * BK + ks * 32 + lk * 8);
        // G fragments (kt) from private LDS
        bf16x8 bgf[2][2];
#pragma unroll
        for (int cb = 0; cb < 2; cb++)
#pragma unroll
            for (int ks = 0; ks < 2; ks++) {
                const int row = cb * 16 + lr, ch = ks * 4 + lk;
                bgf[cb][ks] = *(const bf16x8*)(wbuf + row * 128 + ((ch ^ (row & 7)) * 16));
            }
        // issue G(kt+1) loads (32 dwords live across MFMA-G only)
        float gv[32];
        if (more) {
            const float* s = gsrc + (size_t)(kt + 1) * BK * ID;
#pragma unroll
            for (int j = 0; j < 32; j++) gv[j] = s[(size_t)j * ID];
        }
        __builtin_amdgcn_sched_barrier(0);
        // MFMA G
#pragma unroll
        for (int ks = 0; ks < 2; ks++)
#pragma unroll
            for (int cb = 0; cb < 2; cb++)
#pragma unroll
                for (int mb = 0; mb < 4; mb++)
                    accG[mb][cb] = __builtin_amdgcn_mfma_f32_16x16x32_bf16(af[mb][ks], bgf[cb][ks], accG[mb][cb], 0, 0, 0);
        if (more) {
#pragma unroll
            for (int jj = 0; jj < 4; jj++) {
                const int ch = half * 4 + jj;
                *(uint4*)(wbuf + rowG * 128 + ((ch ^ (rowG & 7)) * 16)) = pack8f(gv + jj * 8);
            }
        }
        // U fragments (kt)
        bf16x8 buf_[2][2];
#pragma unroll
        for (int cb = 0; cb < 2; cb++)
#pragma unroll
            for (int ks = 0; ks < 2; ks++) {
                const int row = 32 + cb * 16 + lr, ch = ks * 4 + lk;
                buf_[cb][ks] = *(const bf16x8*)(wbuf + row * 128 + ((ch ^ (row & 7)) * 16));
            }
        float uv[32];
        if (more) {
            const float* s = usrc + (size_t)(kt + 1) * BK * ID;
#pragma unroll
            for (int j = 0; j < 32; j++) uv[j] = s[(size_t)j * ID];
        }
        __builtin_amdgcn_sched_barrier(0);
        // MFMA U
#pragma unroll
        for (int ks = 0; ks < 2; ks++)
#pragma unroll
            for (int cb = 0; cb < 2; cb++)
#pragma unroll
                for (int mb = 0; mb < 4; mb++)
                    accU[mb][cb] = __builtin_amdgcn_mfma_f32_16x16x32_bf16(af[mb][ks], buf_[cb][ks], accU[mb][cb], 0, 0, 0);
        if (more) {
#pragma unroll
            for (int jj = 0; jj < 4; jj++) {
                const int ch = half * 4 + jj;
                *(uint4*)(wbuf + rowU * 128 + ((ch ^ (rowU & 7)) * 16)) = pack8f(uv + jj * 8);
            }
        }
    }

    // epilogue: in-wave swiglu combine (wave holds both G and U)
    const int gbase = offs[e] + m0;
#pragma unroll
    for (int cb = 0; cb < 2; cb++) {
        const int col = i0 + nh * 32 + cb * 16 + lr;
        const float bgv = bg[e * ID + col];
        const float buv = bu[e * ID + col];
#pragma unroll
        for (int mb = 0; mb < 4; mb++)
#pragma unroll
            for (int q = 0; q < 4; q++) {
                const int row = mh * 64 + mb * 16 + lk * 4 + q;
                if (row < mcount) {
                    float gvv = fminf(accG[mb][cb][q] + bgv, 7.0f);
                    float uvv = fminf(fmaxf(accU[mb][cb][q] + buv, -7.0f), 7.0f);
                    float av = (uvv + 1.0f) * (gvv / (1.0f + __expf(-1.702f * gvv)));
                    act[(size_t)(gbase + row) * ID + col] = bf16bits(av);
                }
            }
    }
}

// ---------------- GEMM2: barrier-free, wave-private W staging ----------------
__global__ __launch_bounds__(256, 3) void k_gemm2(
    const unsigned short* __restrict__ act,
    const float* __restrict__ wd, const float* __restrict__ bd,
    const float* __restrict__ topw,
    const int* __restrict__ cnt, const int* __restrict__ offs,
    const int* __restrict__ list,
    float* __restrict__ out)
{
    const int lin = blockIdx.x;
    const int logical = (lin & 7) * (NB / 8) + (lin >> 3);
    const int mblk = logical & 7;
    const int hblk = (logical >> 3) % NIB;
    const int e = logical / (NIB * NMB);

    const int count = cnt[e];
    const int m0 = mblk * BM;
    if (m0 >= count) return;
    const int mcount = min(BM, count - m0);
    const int h0 = hblk * BN;
    const int tid = threadIdx.x;
    const int gbase = offs[e] + m0;

    const int lane = tid & 63, wid = tid >> 6;
    const int mh = wid >> 1, nh = wid & 1;       // wave tile: 64m x 32h
    const int lr = lane & 15, lk = lane >> 4;

    const unsigned short* arow[4];
#pragma unroll
    for (int mb = 0; mb < 4; mb++) {
        const int r = min(mh * 64 + mb * 16 + lr, mcount - 1);
        arow[mb] = act + (size_t)(gbase + r) * ID;
    }

    const int c = lane & 31, half = lane >> 5;
    const float* wsrc = wd + ((size_t)e * ID + half * 32) * HD + (h0 + nh * 32 + c);

    __shared__ __align__(16) char sB[4][4096];   // per-wave: 32 rows x 128B
    char* const wbuf = sB[wid];
    const int rowW = c;

    f32x4 acc[4][2];
#pragma unroll
    for (int mb = 0; mb < 4; mb++)
#pragma unroll
        for (int cb = 0; cb < 2; cb++) acc[mb][cb] = (f32x4){0.f, 0.f, 0.f, 0.f};

    {   // prologue
        float wv[32];
#pragma unroll
        for (int j = 0; j < 32; j++) wv[j] = wsrc[(size_t)j * HD];
#pragma unroll
        for (int jj = 0; jj < 4; jj++) {
            const int ch = half * 4 + jj;
            *(uint4*)(wbuf + rowW * 128 + ((ch ^ (rowW & 7)) * 16)) = pack8f(wv + jj * 8);
        }
    }

    for (int kt = 0; kt < NKT; kt++) {
        const bool more = (kt + 1 < NKT);
        bf16x8 af[4][2];
#pragma unroll
        for (int mb = 0; mb < 4; mb++)
#pragma unroll
            for (int ks = 0; ks < 2; ks++)
                af[mb][ks] = *(const bf16x8*)(arow[mb] + kt * BK + ks * 32 + lk * 8);
        bf16x8 bwf[2][2];
#pragma unroll
        for (int cb = 0; cb < 2; cb++)
#pragma unroll
            for (int ks = 0; ks < 2; ks++) {
                const int row = cb * 16 + lr, ch = ks * 4 + lk;
                bwf[cb][ks] = *(const bf16x8*)(wbuf + row * 128 + ((ch ^ (row & 7)) * 16));
            }
        float wv[32];
        if (more) {
            const float* s = wsrc + (size_t)(kt + 1) * BK * HD;
#pragma unroll
            for (int j = 0; j < 32; j++) wv[j] = s[(size_t)j * HD];
        }
        __builtin_amdgcn_sched_barrier(0);
#pragma unroll
        for (int ks = 0; ks < 2; ks++)
#pragma unroll
            for (int cb = 0; cb < 2; cb++)
#pragma unroll
                for (int mb = 0; mb < 4; mb++)
                    acc[mb][cb] = __builtin_amdgcn_mfma_f32_16x16x32_bf16(af[mb][ks], bwf[cb][ks], acc[mb][cb], 0, 0, 0);
        if (more) {
#pragma unroll
            for (int jj = 0; jj < 4; jj++) {
                const int ch = half * 4 + jj;
                *(uint4*)(wbuf + rowW * 128 + ((ch ^ (rowW & 7)) * 16)) = pack8f(wv + jj * 8);
            }
        }
    }

#pragma unroll
    for (int mb = 0; mb < 4; mb++)
#pragma unroll
        for (int q = 0; q < 4; q++) {
            const int r = mh * 64 + mb * 16 + lk * 4 + q;
            if (r < mcount) {
                const int idx = list[e * T_TOK + m0 + r];
                const float w = topw[idx];
#pragma unroll
                for (int cb = 0; cb < 2; cb++) {
                    const int col = h0 + nh * 32 + cb * 16 + lr;
                    atomicAdd(&out[(size_t)(idx >> 2) * HD + col], w * (acc[mb][cb][q] + bd[e * HD + col]));
                }
            }
        }
}

extern "C" void kernel_launch(void* const* d_in, const int* in_sizes, int n_in,
                              void* d_out, int out_size, void* d_ws, size_t ws_size,
                              hipStream_t stream)
{
    const float* x  = (const float*)d_in[0];
    const float* rw = (const float*)d_in[1];
    const float* rb = (const float*)d_in[2];
    const float* wg = (const float*)d_in[3];
    const float* bg = (const float*)d_in[4];
    const float* wu = (const float*)d_in[5];
    const float* bu = (const float*)d_in[6];
    const float* wd = (const float*)d_in[7];
    const float* bd = (const float*)d_in[8];
    float* out = (float*)d_out;

    char* ws = (char*)d_ws;
    int*   cnt  = (int*)(ws + 0);
    int*   offs = (int*)(ws + 256);
    float* topw = (float*)(ws + 1024);
    int*   list = (int*)(ws + 32768);
    unsigned short* act = (unsigned short*)(ws + 131072);                         // 4096x2880 bf16
    unsigned short* xbf = (unsigned short*)(ws + 131072 + (size_t)4096 * ID * 2); // 1024x2880 bf16

    hipLaunchKernelGGL(k_init, dim3(T_TOK * HD / 1024), dim3(256), 0, stream, out, cnt);
    hipLaunchKernelGGL(k_xbf, dim3(T_TOK * HD / (256 * 8)), dim3(256), 0, stream, x, xbf);
    hipLaunchKernelGGL(k_router, dim3(T_TOK), dim3(256), 0, stream, x, rw, rb, topw, cnt, list);
    hipLaunchKernelGGL(k_scan, dim3(1), dim3(64), 0, stream, cnt, offs);
    hipLaunchKernelGGL(k_gemm1, dim3(NB), dim3(256), 0, stream,
                       xbf, wg, bg, wu, bu, cnt, offs, list, act);
    hipLaunchKernelGGL(k_gemm2, dim3(NB), dim3(256), 0, stream,
                       act, wd, bd, topw, cnt, offs, list, out);
}